// Round 1
// baseline (806.985 us; speedup 1.0000x reference)
//
#include <hip/hip_runtime.h>

// Problem constants
#define NN  50000   // nodes
#define FD  128     // features
#define NE  800000  // external edges
#define NEI 400000  // internal edges
#define NG  64      // graphs

// Workspace layout (bytes). Everything below ZERO_BYTES is zero-initialized
// each launch via hipMemsetAsync (ws is re-poisoned 0xAA before every call).
#define DEG_EXT_OFF 0        // 50000 int
#define DEG_INT_OFF 200704   // 50000 int
#define EZ_OFF      401408   // 64*128 float
#define IZ_OFF      434176   // 64*128 float
#define CNT_OFF     466944   // 64 int
#define ZERO_BYTES  467200

// -------------------------------------------------------------------------
// Histogram: deg[idx[i]] += 1.  Used for edge-source out-degrees AND for
// per-graph node counts (batch histogram).  softmax([E,1]) == 1, so the
// whole message MLP reduces to these counts.
// -------------------------------------------------------------------------
__global__ __launch_bounds__(256) void hist_kernel(const int* __restrict__ idx,
                                                   int n, int* __restrict__ cnt) {
  int i = blockIdx.x * blockDim.x + threadIdx.x;
  if (i < n) atomicAdd(&cnt[idx[i]], 1);
}

// -------------------------------------------------------------------------
// Fused conv chain.  One block = 64 nodes.  128 threads = (tm 0..7) x (tj 0..15),
// each thread owns an 8x8 register tile (8 rows m, 8 cols j).
// Per chain (ext / int):
//   stage X^T into LDS (XOR-swizzled for conflict-free b128 reads)
//   conv1: GEMM + deg*wcol + bias -> leaky_relu -> row softmax
//   write y^T back into LDS as next input
//   conv2: same
//   scatter: segment-reduced fp32 atomics into group sums
// -------------------------------------------------------------------------
__global__ __launch_bounds__(128) void conv_chain_kernel(
    const float* __restrict__ x,
    const int* __restrict__ deg_ext,
    const int* __restrict__ deg_int,
    const int* __restrict__ batch,
    const float* __restrict__ wu_e1, const float* __restrict__ bu_e1,
    const float* __restrict__ wu_e2, const float* __restrict__ bu_e2,
    const float* __restrict__ wu_i1, const float* __restrict__ bu_i1,
    const float* __restrict__ wu_i2, const float* __restrict__ bu_i2,
    float* __restrict__ ez_sum, float* __restrict__ iz_sum)
{
  // XT[k][m] logical; physical col = 8*((m>>3) ^ (k&7)) + (m&7)  (XOR swizzle)
  __shared__ float XT[FD * 64];      // 32 KB
  // WT[kr][jm(j)] with jm(j) = j + (j>>5)*4, row stride 140 (2-way = free)
  __shared__ float WT[32 * 140];     // 17.5 KB

  const int tid = threadIdx.x;
  const int tm  = tid >> 4;          // 0..7  (row group: m = 8*tm + mi)
  const int tj  = tid & 15;          // 0..15 (col group: j = 8*tj + ji)
  const int mbase = blockIdx.x * 64;

  const int sm  = tid >> 1;          // staging row 0..63
  const int skb = (tid & 1) * 64;    // staging col base 0/64
  const int sg  = sm >> 3, sl = sm & 7;
  const int jmb = 8 * tj + 4 * (tj >> 2);   // WT physical col base

  const float* wu_arr[4] = {wu_e1, wu_e2, wu_i1, wu_i2};
  const float* bu_arr[4] = {bu_e1, bu_e2, bu_i1, bu_i2};

  float acc[8][8];

  for (int chain = 0; chain < 2; ++chain) {
    const int*  deg  = (chain == 0) ? deg_ext : deg_int;
    float*      gsum = (chain == 0) ? ez_sum  : iz_sum;

    // ---- stage X -> XT (transposed + swizzled); zero-fill tail rows
    {
      const int node = mbase + sm;
      const float* xrow = x + (size_t)node * FD + skb;
      #pragma unroll 4
      for (int u = 0; u < 16; ++u) {
        float4 v = make_float4(0.f, 0.f, 0.f, 0.f);
        if (node < NN) v = *(const float4*)(xrow + 4 * u);
        const int k0 = skb + 4 * u;
        XT[(k0 + 0) * 64 + 8 * (sg ^ ((k0 + 0) & 7)) + sl] = v.x;
        XT[(k0 + 1) * 64 + 8 * (sg ^ ((k0 + 1) & 7)) + sl] = v.y;
        XT[(k0 + 2) * 64 + 8 * (sg ^ ((k0 + 2) & 7)) + sl] = v.z;
        XT[(k0 + 3) * 64 + 8 * (sg ^ ((k0 + 3) & 7)) + sl] = v.w;
      }
    }
    __syncthreads();

    for (int cv = 0; cv < 2; ++cv) {
      const float* wu = wu_arr[chain * 2 + cv];
      const float* bu = bu_arr[chain * 2 + cv];

      #pragma unroll
      for (int a = 0; a < 8; ++a)
        #pragma unroll
        for (int b = 0; b < 8; ++b) acc[a][b] = 0.f;

      for (int kk = 0; kk < FD; kk += 32) {
        // stage W^T chunk: thread t owns column j = t
        {
          const float* wrow = wu + (size_t)tid * 129 + kk;   // wu[j][kk..kk+31]
          const int wjm = tid + (tid >> 5) * 4;
          #pragma unroll 8
          for (int i = 0; i < 32; ++i) WT[i * 140 + wjm] = wrow[i];
        }
        __syncthreads();

        #pragma unroll 4
        for (int kr = 0; kr < 32; ++kr) {
          const int k = kk + kr;
          const float* xp = &XT[k * 64 + 8 * (tm ^ (k & 7))];
          const float4 xa = *(const float4*)xp;
          const float4 xb = *(const float4*)(xp + 4);
          const float* wp = &WT[kr * 140 + jmb];
          const float4 wa = *(const float4*)wp;
          const float4 wb = *(const float4*)(wp + 4);
          const float xs[8]  = {xa.x, xa.y, xa.z, xa.w, xb.x, xb.y, xb.z, xb.w};
          const float wsv[8] = {wa.x, wa.y, wa.z, wa.w, wb.x, wb.y, wb.z, wb.w};
          #pragma unroll
          for (int mi = 0; mi < 8; ++mi)
            #pragma unroll
            for (int ji = 0; ji < 8; ++ji)
              acc[mi][ji] = fmaf(xs[mi], wsv[ji], acc[mi][ji]);
        }
        __syncthreads();
      }

      // ---- epilogue: + deg*wcol + bias, leaky_relu, row softmax
      float wcol[8], bias[8];
      #pragma unroll
      for (int ji = 0; ji < 8; ++ji) {
        const int j = 8 * tj + ji;
        wcol[ji] = wu[(size_t)j * 129 + 128];  // last column multiplies node_msg
        bias[ji] = bu[j];
      }
      #pragma unroll
      for (int mi = 0; mi < 8; ++mi) {
        const int node = mbase + 8 * tm + mi;
        const float dg = (node < NN) ? (float)deg[node] : 0.f;
        float mx = -3.4e38f;
        #pragma unroll
        for (int ji = 0; ji < 8; ++ji) {
          float v = fmaf(dg, wcol[ji], acc[mi][ji] + bias[ji]);
          v = (v > 0.f) ? v : 0.01f * v;            // leaky_relu
          acc[mi][ji] = v;
          mx = fmaxf(mx, v);
        }
        // row (128-wide) reduction across the 16-lane tj group
        mx = fmaxf(mx, __shfl_xor(mx, 1));
        mx = fmaxf(mx, __shfl_xor(mx, 2));
        mx = fmaxf(mx, __shfl_xor(mx, 4));
        mx = fmaxf(mx, __shfl_xor(mx, 8));
        float s = 0.f;
        #pragma unroll
        for (int ji = 0; ji < 8; ++ji) {
          const float e = __expf(acc[mi][ji] - mx);
          acc[mi][ji] = e;
          s += e;
        }
        s += __shfl_xor(s, 1);
        s += __shfl_xor(s, 2);
        s += __shfl_xor(s, 4);
        s += __shfl_xor(s, 8);
        const float inv = 1.f / s;
        #pragma unroll
        for (int ji = 0; ji < 8; ++ji) acc[mi][ji] *= inv;
      }

      if (cv == 0) {
        // write y^T into XT as next conv's input (j becomes k; j&7 == ji)
        #pragma unroll
        for (int ji = 0; ji < 8; ++ji) {
          const int j = 8 * tj + ji;
          float* p = &XT[j * 64 + 8 * (tm ^ ji)];
          *(float4*)p       = make_float4(acc[0][ji], acc[1][ji], acc[2][ji], acc[3][ji]);
          *(float4*)(p + 4) = make_float4(acc[4][ji], acc[5][ji], acc[6][ji], acc[7][ji]);
        }
      }
    }

    // ---- scatter into per-graph sums (batch is sorted: segment fast path)
    {
      const int node0 = mbase + 8 * tm;
      bool fast = (node0 + 7 < NN);
      int g0 = 0, g7 = -1;
      if (fast) { g0 = batch[node0]; g7 = batch[node0 + 7]; }
      if (fast && g0 == g7) {
        #pragma unroll
        for (int ji = 0; ji < 8; ++ji) {
          float s = 0.f;
          #pragma unroll
          for (int mi = 0; mi < 8; ++mi) s += acc[mi][ji];
          atomicAdd(&gsum[g0 * FD + 8 * tj + ji], s);
        }
      } else {
        for (int mi = 0; mi < 8; ++mi) {
          const int node = node0 + mi;
          if (node < NN) {
            const int g = batch[node];
            #pragma unroll
            for (int ji = 0; ji < 8; ++ji)
              atomicAdd(&gsum[g * FD + 8 * tj + ji], acc[mi][ji]);
          }
        }
      }
    }
    __syncthreads();   // XT safe to restage for chain 1
  }
}

// -------------------------------------------------------------------------
// Final MLP: 8 blocks x 8 graphs.  z = [ez|iz]/cnt -> relu(z@fc1^T+b1) -> @fc2^T+b2
// -------------------------------------------------------------------------
__global__ __launch_bounds__(256) void fc_kernel(
    const float* __restrict__ ez_sum, const float* __restrict__ iz_sum,
    const int* __restrict__ cnt,
    const float* __restrict__ fc1_w, const float* __restrict__ fc1_b,
    const float* __restrict__ fc2_w, const float* __restrict__ fc2_b,
    float* __restrict__ out)
{
  __shared__ float z8[8 * 256];   // 8 graphs x 256 features
  __shared__ float h8[8 * 129];   // 8 graphs x 128 hidden (+1 pad)
  const int t = threadIdx.x;
  const int gbase = blockIdx.x * 8;

  for (int idx = t; idx < 8 * 256; idx += 256) {
    const int gl = idx >> 8, c = idx & 255;
    const int g = gbase + gl;
    const float denom = fmaxf((float)cnt[g], 1.0f);
    const float v = (c < 128 ? ez_sum[g * 128 + c] : iz_sum[g * 128 + (c - 128)]);
    z8[idx] = v / denom;
  }
  __syncthreads();

  // thread t -> output o = t&127, graph half gh = t>>7 (4 graphs each)
  {
    const int o = t & 127;
    const int gh = t >> 7;
    const float* w = fc1_w + (size_t)o * 256;
    float a0 = fc1_b[o], a1 = a0, a2 = a0, a3 = a0;
    const float* z0 = &z8[(gh * 4 + 0) * 256];
    const float* z1 = &z8[(gh * 4 + 1) * 256];
    const float* z2 = &z8[(gh * 4 + 2) * 256];
    const float* z3 = &z8[(gh * 4 + 3) * 256];
    for (int c = 0; c < 256; c += 4) {
      const float4 wv = *(const float4*)(w + c);
      const float4 v0 = *(const float4*)(z0 + c);
      const float4 v1 = *(const float4*)(z1 + c);
      const float4 v2 = *(const float4*)(z2 + c);
      const float4 v3 = *(const float4*)(z3 + c);
      a0 += wv.x * v0.x + wv.y * v0.y + wv.z * v0.z + wv.w * v0.w;
      a1 += wv.x * v1.x + wv.y * v1.y + wv.z * v1.z + wv.w * v1.w;
      a2 += wv.x * v2.x + wv.y * v2.y + wv.z * v2.z + wv.w * v2.w;
      a3 += wv.x * v3.x + wv.y * v3.y + wv.z * v3.z + wv.w * v3.w;
    }
    h8[(gh * 4 + 0) * 129 + o] = fmaxf(a0, 0.f);
    h8[(gh * 4 + 1) * 129 + o] = fmaxf(a1, 0.f);
    h8[(gh * 4 + 2) * 129 + o] = fmaxf(a2, 0.f);
    h8[(gh * 4 + 3) * 129 + o] = fmaxf(a3, 0.f);
  }
  __syncthreads();

  if (t < 8) {
    const float* hh = &h8[t * 129];
    float a = fc2_b[0];
    for (int o = 0; o < 128; ++o) a += hh[o] * fc2_w[o];
    out[gbase + t] = a;
  }
}

// -------------------------------------------------------------------------
extern "C" void kernel_launch(void* const* d_in, const int* in_sizes, int n_in,
                              void* d_out, int out_size, void* d_ws, size_t ws_size,
                              hipStream_t stream) {
  const float* x                   = (const float*)d_in[0];
  const int*   edge_index          = (const int*)  d_in[1];   // [2,E]: first E = sources
  const int*   internal_edge_index = (const int*)  d_in[3];
  const int*   batch               = (const int*)  d_in[5];
  const float* wu_e1 = (const float*)d_in[8];
  const float* bu_e1 = (const float*)d_in[9];
  const float* wu_e2 = (const float*)d_in[12];
  const float* bu_e2 = (const float*)d_in[13];
  const float* wu_i1 = (const float*)d_in[16];
  const float* bu_i1 = (const float*)d_in[17];
  const float* wu_i2 = (const float*)d_in[20];
  const float* bu_i2 = (const float*)d_in[21];
  const float* fc1_w = (const float*)d_in[22];
  const float* fc1_b = (const float*)d_in[23];
  const float* fc2_w = (const float*)d_in[24];
  const float* fc2_b = (const float*)d_in[25];

  char* ws = (char*)d_ws;
  int*   deg_ext = (int*)  (ws + DEG_EXT_OFF);
  int*   deg_int = (int*)  (ws + DEG_INT_OFF);
  float* ez      = (float*)(ws + EZ_OFF);
  float* iz      = (float*)(ws + IZ_OFF);
  int*   cnt     = (int*)  (ws + CNT_OFF);

  hipMemsetAsync(d_ws, 0, ZERO_BYTES, stream);
  hist_kernel<<<(NE  + 255) / 256, 256, 0, stream>>>(edge_index,          NE,  deg_ext);
  hist_kernel<<<(NEI + 255) / 256, 256, 0, stream>>>(internal_edge_index, NEI, deg_int);
  hist_kernel<<<(NN  + 255) / 256, 256, 0, stream>>>(batch,               NN,  cnt);

  conv_chain_kernel<<<(NN + 63) / 64, 128, 0, stream>>>(
      x, deg_ext, deg_int, batch,
      wu_e1, bu_e1, wu_e2, bu_e2, wu_i1, bu_i1, wu_i2, bu_i2,
      ez, iz);

  fc_kernel<<<8, 256, 0, stream>>>(ez, iz, cnt, fc1_w, fc1_b, fc2_w, fc2_b,
                                   (float*)d_out);
}

// Round 2
// 446.869 us; speedup vs baseline: 1.8059x; 1.8059x over previous
//
#include <hip/hip_runtime.h>

// Problem constants
#define NN  50000   // nodes
#define FD  128     // features
#define NE  800000  // external edges
#define NEI 400000  // internal edges
#define NG  64      // graphs

// Workspace layout (bytes). [0, ZERO_BYTES) is zeroed each launch.
#define DEG_EXT_OFF 0        // 50000 int
#define DEG_INT_OFF 200704   // 50000 int
#define EZ_OFF      401408   // 64*128 float
#define IZ_OFF      434176   // 64*128 float
#define CNT_OFF     466944   // 64 int
#define ZERO_BYTES  467200
#define WT_OFF      467200   // 4 * 129*128 float (transposed W, row 128 = node_msg col)
#define WT_CONV_STRIDE 16512 // 129*128 floats

// -------------------------------------------------------------------------
// Transpose the 4 update-weight matrices: wt[c][k][j] = wu_c[j][k], k=0..128
// (k=128 row is the node_msg column).  Tiny, runs once per launch.
// -------------------------------------------------------------------------
__global__ __launch_bounds__(256) void transpose_w_kernel(
    const float* __restrict__ w0, const float* __restrict__ w1,
    const float* __restrict__ w2, const float* __restrict__ w3,
    float* __restrict__ wt)
{
  const float* src = (blockIdx.x == 0) ? w0 : (blockIdx.x == 1) ? w1
                   : (blockIdx.x == 2) ? w2 : w3;
  float* dst = wt + (size_t)blockIdx.x * WT_CONV_STRIDE;
  for (int idx = threadIdx.x; idx < WT_CONV_STRIDE; idx += 256) {
    const int k = idx >> 7, j = idx & 127;       // k in 0..128
    dst[idx] = src[j * 129 + k];
  }
}

// -------------------------------------------------------------------------
// All histograms in one kernel.  softmax([E,1]) == 1, so the message MLP
// reduces to out-degree counts.  Batch is SORTED -> naive global atomics
// serialize 50k ops on 64 addresses; privatize in LDS instead.
// -------------------------------------------------------------------------
#define HB_EXT 782   // ceil(NE/1024)
#define HB_INT 391   // ceil(NEI/1024)
#define HB_BAT 13    // ceil(NN/4096)

__global__ __launch_bounds__(256) void hist_all_kernel(
    const int* __restrict__ ei, const int* __restrict__ iei,
    const int* __restrict__ batch,
    int* __restrict__ deg_ext, int* __restrict__ deg_int, int* __restrict__ cnt)
{
  const int b = blockIdx.x, t = threadIdx.x;
  if (b < HB_EXT) {
    const int base = b * 1024 + t;
    #pragma unroll
    for (int u = 0; u < 4; ++u) {
      const int i = base + u * 256;
      if (i < NE) atomicAdd(&deg_ext[ei[i]], 1);
    }
  } else if (b < HB_EXT + HB_INT) {
    const int base = (b - HB_EXT) * 1024 + t;
    #pragma unroll
    for (int u = 0; u < 4; ++u) {
      const int i = base + u * 256;
      if (i < NEI) atomicAdd(&deg_int[iei[i]], 1);
    }
  } else {
    __shared__ int h[64];
    if (t < 64) h[t] = 0;
    __syncthreads();
    const int base = (b - HB_EXT - HB_INT) * 4096 + t;
    for (int u = 0; u < 16; ++u) {
      const int i = base + u * 256;
      if (i < NN) atomicAdd(&h[batch[i]], 1);
    }
    __syncthreads();
    if (t < 64 && h[t]) atomicAdd(&cnt[t], h[t]);
  }
}

// -------------------------------------------------------------------------
// Fused conv chain.  Grid (782, 2): x = 64-node tile, y = chain (ext/int).
// 256 threads = (tm 0..15) x (tj 0..15); thread tile = 4 rows x 8 cols.
// XT[k][m] XOR-swizzled (phys col = 8*((m>>3)^(k&7)) + (m&7)); WT unpadded
// stride-128 (2-way bank aliasing = free).  LDS 48 KB -> 3 blocks/CU,
// 12 waves/CU.
// -------------------------------------------------------------------------
__global__ __launch_bounds__(256, 3) void conv_chain_kernel(
    const float* __restrict__ x,
    const int* __restrict__ deg_ext, const int* __restrict__ deg_int,
    const int* __restrict__ batch,
    const float* __restrict__ wt,
    const float* __restrict__ bu_e1, const float* __restrict__ bu_e2,
    const float* __restrict__ bu_i1, const float* __restrict__ bu_i2,
    float* __restrict__ ez_sum, float* __restrict__ iz_sum)
{
  __shared__ float XT[FD * 64];   // 32 KB
  __shared__ float WT[32 * FD];   // 16 KB

  const int tid = threadIdx.x;
  const int tj  = tid & 15;          // col group: j = 8*tj + ji
  const int tm  = tid >> 4;          // row group: m = 4*tm + mi
  const int mbase = blockIdx.x * 64;
  const int chain = blockIdx.y;

  const int*  deg  = chain ? deg_int : deg_ext;
  float*      gsum = chain ? iz_sum  : ez_sum;
  const float* bu0 = chain ? bu_i1 : bu_e1;
  const float* bu1 = chain ? bu_i2 : bu_e2;

  // ---- stage X -> XT (transposed + swizzled); zero-fill tail rows
  {
    const int node = mbase + (tid >> 2);
    const int q    = (tid & 3) * 32;
    const int sg   = tid >> 5;          // (node_local)>>3
    const int sl   = (tid >> 2) & 7;
    const float* xr = x + (size_t)node * FD + q;
    #pragma unroll
    for (int u = 0; u < 8; ++u) {
      float4 v = make_float4(0.f, 0.f, 0.f, 0.f);
      if (node < NN) v = *(const float4*)(xr + 4 * u);
      const int k0 = q + 4 * u;
      XT[(k0 + 0) * 64 + 8 * (sg ^ ((k0 + 0) & 7)) + sl] = v.x;
      XT[(k0 + 1) * 64 + 8 * (sg ^ ((k0 + 1) & 7)) + sl] = v.y;
      XT[(k0 + 2) * 64 + 8 * (sg ^ ((k0 + 2) & 7)) + sl] = v.z;
      XT[(k0 + 3) * 64 + 8 * (sg ^ ((k0 + 3) & 7)) + sl] = v.w;
    }
  }
  __syncthreads();

  const int th   = tm >> 1;        // m>>3 (octet of this thread's 4 rows)
  const int xoff = 4 * (tm & 1);   // m&7 base within octet

  float acc[4][8];

  for (int cv = 0; cv < 2; ++cv) {
    const float* wtc = wt + (size_t)(chain * 2 + cv) * WT_CONV_STRIDE;
    const float* bu  = cv ? bu1 : bu0;

    #pragma unroll
    for (int a = 0; a < 4; ++a)
      #pragma unroll
      for (int b = 0; b < 8; ++b) acc[a][b] = 0.f;

    for (int kk = 0; kk < FD; kk += 32) {
      // stage WT chunk (coalesced float4 from pre-transposed global W)
      {
        const float* src = wtc + kk * FD;
        #pragma unroll
        for (int u = 0; u < 4; ++u) {
          const int e = u * 1024 + tid * 4;
          *(float4*)&WT[e] = *(const float4*)(src + e);
        }
      }
      __syncthreads();

      #pragma unroll 4
      for (int kr = 0; kr < 32; ++kr) {
        const int k = kk + kr;
        const float4 xa = *(const float4*)&XT[k * 64 + 8 * (th ^ (k & 7)) + xoff];
        const float* wp = &WT[kr * FD + 8 * tj];
        const float4 wa = *(const float4*)wp;
        const float4 wb = *(const float4*)(wp + 4);
        const float xs[4] = {xa.x, xa.y, xa.z, xa.w};
        const float wv[8] = {wa.x, wa.y, wa.z, wa.w, wb.x, wb.y, wb.z, wb.w};
        #pragma unroll
        for (int mi = 0; mi < 4; ++mi)
          #pragma unroll
          for (int ji = 0; ji < 8; ++ji)
            acc[mi][ji] = fmaf(xs[mi], wv[ji], acc[mi][ji]);
      }
      __syncthreads();
    }

    // ---- epilogue: + deg*wcol + bias, leaky_relu, row softmax
    float wcol[8], bias[8];
    {
      const float* wc = wtc + 128 * FD + 8 * tj;   // row k=128 = node_msg col
      const float4 c0 = *(const float4*)wc;
      const float4 c1 = *(const float4*)(wc + 4);
      wcol[0]=c0.x; wcol[1]=c0.y; wcol[2]=c0.z; wcol[3]=c0.w;
      wcol[4]=c1.x; wcol[5]=c1.y; wcol[6]=c1.z; wcol[7]=c1.w;
      const float* bp = bu + 8 * tj;
      const float4 b0 = *(const float4*)bp;
      const float4 b1 = *(const float4*)(bp + 4);
      bias[0]=b0.x; bias[1]=b0.y; bias[2]=b0.z; bias[3]=b0.w;
      bias[4]=b1.x; bias[5]=b1.y; bias[6]=b1.z; bias[7]=b1.w;
    }
    #pragma unroll
    for (int mi = 0; mi < 4; ++mi) {
      const int node = mbase + 4 * tm + mi;
      const float dg = (node < NN) ? (float)deg[node] : 0.f;
      float mx = -3.4e38f;
      #pragma unroll
      for (int ji = 0; ji < 8; ++ji) {
        float v = fmaf(dg, wcol[ji], acc[mi][ji] + bias[ji]);
        v = (v > 0.f) ? v : 0.01f * v;            // leaky_relu
        acc[mi][ji] = v;
        mx = fmaxf(mx, v);
      }
      mx = fmaxf(mx, __shfl_xor(mx, 1));
      mx = fmaxf(mx, __shfl_xor(mx, 2));
      mx = fmaxf(mx, __shfl_xor(mx, 4));
      mx = fmaxf(mx, __shfl_xor(mx, 8));
      float s = 0.f;
      #pragma unroll
      for (int ji = 0; ji < 8; ++ji) {
        const float e = __expf(acc[mi][ji] - mx);
        acc[mi][ji] = e;
        s += e;
      }
      s += __shfl_xor(s, 1);
      s += __shfl_xor(s, 2);
      s += __shfl_xor(s, 4);
      s += __shfl_xor(s, 8);
      const float inv = 1.f / s;
      #pragma unroll
      for (int ji = 0; ji < 8; ++ji) acc[mi][ji] *= inv;
    }

    if (cv == 0) {
      // write y^T into XT as conv2 input (last chunk barrier already ensured
      // all XT reads are done; per-thread destinations are disjoint)
      #pragma unroll
      for (int ji = 0; ji < 8; ++ji) {
        const int j = 8 * tj + ji;
        *(float4*)&XT[j * 64 + 8 * (th ^ (j & 7)) + xoff] =
            make_float4(acc[0][ji], acc[1][ji], acc[2][ji], acc[3][ji]);
      }
      // conv2's first WT-stage barrier covers visibility of these writes
    }
  }

  // ---- scatter into per-graph sums (batch sorted: segment fast path)
  {
    const int node0 = mbase + 4 * tm;
    if (node0 + 3 < NN && batch[node0] == batch[node0 + 3]) {
      const int g = batch[node0];
      #pragma unroll
      for (int ji = 0; ji < 8; ++ji) {
        const float s = acc[0][ji] + acc[1][ji] + acc[2][ji] + acc[3][ji];
        atomicAdd(&gsum[g * FD + 8 * tj + ji], s);
      }
    } else {
      for (int mi = 0; mi < 4; ++mi) {
        const int node = node0 + mi;
        if (node < NN) {
          const int g = batch[node];
          #pragma unroll
          for (int ji = 0; ji < 8; ++ji)
            atomicAdd(&gsum[g * FD + 8 * tj + ji], acc[mi][ji]);
        }
      }
    }
  }
}

// -------------------------------------------------------------------------
// Final MLP: 8 blocks x 8 graphs.  z = [ez|iz]/cnt -> relu(z@fc1^T+b1) -> @fc2^T+b2
// -------------------------------------------------------------------------
__global__ __launch_bounds__(256) void fc_kernel(
    const float* __restrict__ ez_sum, const float* __restrict__ iz_sum,
    const int* __restrict__ cnt,
    const float* __restrict__ fc1_w, const float* __restrict__ fc1_b,
    const float* __restrict__ fc2_w, const float* __restrict__ fc2_b,
    float* __restrict__ out)
{
  __shared__ float z8[8 * 256];
  __shared__ float h8[8 * 129];
  const int t = threadIdx.x;
  const int gbase = blockIdx.x * 8;

  for (int idx = t; idx < 8 * 256; idx += 256) {
    const int gl = idx >> 8, c = idx & 255;
    const int g = gbase + gl;
    const float denom = fmaxf((float)cnt[g], 1.0f);
    const float v = (c < 128 ? ez_sum[g * 128 + c] : iz_sum[g * 128 + (c - 128)]);
    z8[idx] = v / denom;
  }
  __syncthreads();

  {
    const int o = t & 127;
    const int gh = t >> 7;
    const float* w = fc1_w + (size_t)o * 256;
    float a0 = fc1_b[o], a1 = a0, a2 = a0, a3 = a0;
    const float* z0 = &z8[(gh * 4 + 0) * 256];
    const float* z1 = &z8[(gh * 4 + 1) * 256];
    const float* z2 = &z8[(gh * 4 + 2) * 256];
    const float* z3 = &z8[(gh * 4 + 3) * 256];
    for (int c = 0; c < 256; c += 4) {
      const float4 wv = *(const float4*)(w + c);
      const float4 v0 = *(const float4*)(z0 + c);
      const float4 v1 = *(const float4*)(z1 + c);
      const float4 v2 = *(const float4*)(z2 + c);
      const float4 v3 = *(const float4*)(z3 + c);
      a0 += wv.x * v0.x + wv.y * v0.y + wv.z * v0.z + wv.w * v0.w;
      a1 += wv.x * v1.x + wv.y * v1.y + wv.z * v1.z + wv.w * v1.w;
      a2 += wv.x * v2.x + wv.y * v2.y + wv.z * v2.z + wv.w * v2.w;
      a3 += wv.x * v3.x + wv.y * v3.y + wv.z * v3.z + wv.w * v3.w;
    }
    h8[(gh * 4 + 0) * 129 + o] = fmaxf(a0, 0.f);
    h8[(gh * 4 + 1) * 129 + o] = fmaxf(a1, 0.f);
    h8[(gh * 4 + 2) * 129 + o] = fmaxf(a2, 0.f);
    h8[(gh * 4 + 3) * 129 + o] = fmaxf(a3, 0.f);
  }
  __syncthreads();

  if (t < 8) {
    const float* hh = &h8[t * 129];
    float a = fc2_b[0];
    for (int o = 0; o < 128; ++o) a += hh[o] * fc2_w[o];
    out[gbase + t] = a;
  }
}

// -------------------------------------------------------------------------
extern "C" void kernel_launch(void* const* d_in, const int* in_sizes, int n_in,
                              void* d_out, int out_size, void* d_ws, size_t ws_size,
                              hipStream_t stream) {
  const float* x                   = (const float*)d_in[0];
  const int*   edge_index          = (const int*)  d_in[1];   // [2,E]: first E = sources
  const int*   internal_edge_index = (const int*)  d_in[3];
  const int*   batch               = (const int*)  d_in[5];
  const float* wu_e1 = (const float*)d_in[8];
  const float* bu_e1 = (const float*)d_in[9];
  const float* wu_e2 = (const float*)d_in[12];
  const float* bu_e2 = (const float*)d_in[13];
  const float* wu_i1 = (const float*)d_in[16];
  const float* bu_i1 = (const float*)d_in[17];
  const float* wu_i2 = (const float*)d_in[20];
  const float* bu_i2 = (const float*)d_in[21];
  const float* fc1_w = (const float*)d_in[22];
  const float* fc1_b = (const float*)d_in[23];
  const float* fc2_w = (const float*)d_in[24];
  const float* fc2_b = (const float*)d_in[25];

  char* ws = (char*)d_ws;
  int*   deg_ext = (int*)  (ws + DEG_EXT_OFF);
  int*   deg_int = (int*)  (ws + DEG_INT_OFF);
  float* ez      = (float*)(ws + EZ_OFF);
  float* iz      = (float*)(ws + IZ_OFF);
  int*   cnt     = (int*)  (ws + CNT_OFF);
  float* wt      = (float*)(ws + WT_OFF);

  hipMemsetAsync(d_ws, 0, ZERO_BYTES, stream);

  transpose_w_kernel<<<4, 256, 0, stream>>>(wu_e1, wu_e2, wu_i1, wu_i2, wt);

  hist_all_kernel<<<HB_EXT + HB_INT + HB_BAT, 256, 0, stream>>>(
      edge_index, internal_edge_index, batch, deg_ext, deg_int, cnt);

  conv_chain_kernel<<<dim3((NN + 63) / 64, 2), 256, 0, stream>>>(
      x, deg_ext, deg_int, batch, wt,
      bu_e1, bu_e2, bu_i1, bu_i2, ez, iz);

  fc_kernel<<<8, 256, 0, stream>>>(ez, iz, cnt, fc1_w, fc1_b, fc2_w, fc2_b,
                                   (float*)d_out);
}

// Round 3
// 250.363 us; speedup vs baseline: 3.2233x; 1.7849x over previous
//
#include <hip/hip_runtime.h>

// Problem constants
#define NN  50000   // nodes
#define FD  128     // features
#define NE  800000  // external edges
#define NEI 400000  // internal edges
#define NG  64      // graphs

// Workspace layout (bytes). [0, ZERO_BYTES) is zeroed each launch.
#define DEG_EXT_OFF 0        // 50000 int
#define DEG_INT_OFF 200704   // 50000 int
#define EZ_OFF      401408   // 64*128 float
#define IZ_OFF      434176   // 64*128 float
#define CNT_OFF     466944   // 64 int
#define ZERO_BYTES  467200
// B fragments: 4 convs x [ (ct 0..7, kc 0..3, part 0..1) x 64 lanes x 8 ushort ]
#define WB_OFF      467200   // 4 * 32768 ushort = 256 KB
#define WCOL_OFF    729344   // 4 * 128 float = 2 KB   (total 731392 B, same as R2)

typedef short  short8 __attribute__((ext_vector_type(8)));
typedef float  f32x4  __attribute__((ext_vector_type(4)));

__device__ __forceinline__ unsigned short bf16h(float f) {
  unsigned int u = __float_as_uint(f);
  u += 0x7FFFu + ((u >> 16) & 1u);            // RNE
  return (unsigned short)(u >> 16);
}
__device__ __forceinline__ float bf16tof(unsigned short h) {
  return __uint_as_float(((unsigned int)h) << 16);
}

// -------------------------------------------------------------------------
// Prep (blocks 0..3): convert wu_c into MFMA B-fragments (hi/lo bf16),
// lane-packed so conv waves load them with one dwordx4 per fragment.
// B[k][n] = wu[n][k]; lane holds n=lane&15, k=kc*32+(lane>>4)*8+j  (8 consec k
// of a wu row -> contiguous reads, no transpose needed).
// Hist (blocks 4..): out-degree histograms (softmax([E,1])==1 -> message MLP
// reduces to counts) + LDS-privatized batch histogram (batch is sorted).
// -------------------------------------------------------------------------
#define HB_EXT 782
#define HB_INT 391
#define HB_BAT 13

__global__ __launch_bounds__(256) void prep_hist_kernel(
    const float* __restrict__ wu_e1, const float* __restrict__ wu_e2,
    const float* __restrict__ wu_i1, const float* __restrict__ wu_i2,
    const int* __restrict__ ei, const int* __restrict__ iei,
    const int* __restrict__ batch,
    unsigned short* __restrict__ WB, float* __restrict__ wcolp,
    int* __restrict__ deg_ext, int* __restrict__ deg_int, int* __restrict__ cnt)
{
  const int b = blockIdx.x, t = threadIdx.x;
  if (b < 4) {
    const float* wu = (b == 0) ? wu_e1 : (b == 1) ? wu_e2 : (b == 2) ? wu_i1 : wu_i2;
    const int lane = t & 63, u = t >> 6;
    const int n = lane & 15, quad = lane >> 4;
    unsigned short* wb = WB + b * 32768;
    #pragma unroll
    for (int cc = 0; cc < 2; ++cc) {
      const int ct = u + 4 * cc;
      const int j = ct * 16 + n;
      #pragma unroll
      for (int kc = 0; kc < 4; ++kc) {
        const int k0 = kc * 32 + quad * 8;
        const float* src = wu + (size_t)j * 129 + k0;
        short8 hi, lo;
        #pragma unroll
        for (int e = 0; e < 8; ++e) {
          const float v = src[e];
          const unsigned short h = bf16h(v);
          hi[e] = (short)h;
          lo[e] = (short)bf16h(v - bf16tof(h));
        }
        const int fbase = ((ct * 4 + kc) * 2) * 512 + lane * 8;
        *(short8*)&wb[fbase]       = hi;
        *(short8*)&wb[fbase + 512] = lo;
      }
    }
    if (t < 128) wcolp[b * 128 + t] = wu[(size_t)t * 129 + 128];
  } else if (b < 4 + HB_EXT) {
    const int base = (b - 4) * 1024 + t;
    #pragma unroll
    for (int u = 0; u < 4; ++u) {
      const int i = base + u * 256;
      if (i < NE) atomicAdd(&deg_ext[ei[i]], 1);
    }
  } else if (b < 4 + HB_EXT + HB_INT) {
    const int base = (b - 4 - HB_EXT) * 1024 + t;
    #pragma unroll
    for (int u = 0; u < 4; ++u) {
      const int i = base + u * 256;
      if (i < NEI) atomicAdd(&deg_int[iei[i]], 1);
    }
  } else {
    __shared__ int h[64];
    if (t < 64) h[t] = 0;
    __syncthreads();
    const int base = (b - 4 - HB_EXT - HB_INT) * 4096 + t;
    for (int u = 0; u < 16; ++u) {
      const int i = base + u * 256;
      if (i < NN) atomicAdd(&h[batch[i]], 1);
    }
    __syncthreads();
    if (t < 64 && h[t]) atomicAdd(&cnt[t], h[t]);
  }
}

// -------------------------------------------------------------------------
// Fused conv chain via split-bf16 MFMA (hi+lo; 4 terms ~= fp32 precision).
// Grid (782, 2): x = 64-node tile, y = chain.  256 threads = 4 waves.
// Wave w: col-tiles {2w, 2w+1} (32 cols), all 4 row-tiles; acc = 8 f32x4.
// A (X then y) lives in LDS in fragment order -> stride-1 ds_read_b128.
// B fragments live in VGPRs for the whole conv (loaded from prepped WB).
// mfma_f32_16x16x32_bf16 layouts (HW-verified):
//   A: m=lane&15, k=(lane>>4)*8+j ; B: n=lane&15, k=(lane>>4)*8+j
//   D: col=lane&15, row=(lane>>4)*4+reg
// -------------------------------------------------------------------------
__global__ __launch_bounds__(256, 3) void conv_mfma_kernel(
    const float* __restrict__ x,
    const int* __restrict__ deg_ext, const int* __restrict__ deg_int,
    const int* __restrict__ batch,
    const unsigned short* __restrict__ WB, const float* __restrict__ wcolp,
    const float* __restrict__ bu_e1, const float* __restrict__ bu_e2,
    const float* __restrict__ bu_i1, const float* __restrict__ bu_i2,
    float* __restrict__ ez_sum, float* __restrict__ iz_sum)
{
  __shared__ unsigned short XT[2 * 8192];   // [part][rt*4+kc][lane][8]  32 KB
  __shared__ float degs[64];
  __shared__ float red[64 * 4];
  __shared__ float invb[64];

  const int tid  = threadIdx.x;
  const int lane = tid & 63;
  const int w    = tid >> 6;        // wave 0..3
  const int n    = lane & 15;
  const int quad = lane >> 4;
  const int mbase = blockIdx.x * 64;
  const int chain = blockIdx.y;

  const int*  deg  = chain ? deg_int : deg_ext;
  float*      gsum = chain ? iz_sum  : ez_sum;
  const float* bu0 = chain ? bu_i1 : bu_e1;
  const float* bu1 = chain ? bu_i2 : bu_e2;

  // ---- stage X -> A fragments (hi/lo) ; wave w handles k-chunk kc=w.
  {
    const int kc = w;
    #pragma unroll
    for (int rt = 0; rt < 4; ++rt) {
      const int node = mbase + rt * 16 + n;
      const float* xr = x + (size_t)node * FD + kc * 32 + quad * 8;
      float4 a = make_float4(0.f, 0.f, 0.f, 0.f), bb = a;
      if (node < NN) { a = *(const float4*)xr; bb = *(const float4*)(xr + 4); }
      const float v[8] = {a.x, a.y, a.z, a.w, bb.x, bb.y, bb.z, bb.w};
      short8 hi, lo;
      #pragma unroll
      for (int e = 0; e < 8; ++e) {
        const unsigned short h = bf16h(v[e]);
        hi[e] = (short)h;
        lo[e] = (short)bf16h(v[e] - bf16tof(h));
      }
      const int idx = ((rt * 4 + kc) * 64 + lane) * 8;
      *(short8*)&XT[idx]        = hi;
      *(short8*)&XT[8192 + idx] = lo;
    }
    if (tid < 64) degs[tid] = (mbase + tid < NN) ? (float)deg[mbase + tid] : 0.f;
  }
  __syncthreads();

  f32x4 acc[4][2];

  for (int cv = 0; cv < 2; ++cv) {
    const int conv = chain * 2 + cv;
    const float* bu = cv ? bu1 : bu0;

    // ---- load B fragments into registers (held for whole conv)
    short8 Bf[2][4][2];
    {
      const unsigned short* wb = WB + conv * 32768 + lane * 8;
      #pragma unroll
      for (int cti = 0; cti < 2; ++cti) {
        const int ct = w * 2 + cti;
        #pragma unroll
        for (int kc = 0; kc < 4; ++kc) {
          const int fb = ((ct * 4 + kc) * 2) * 512;
          Bf[cti][kc][0] = *(const short8*)&wb[fb];
          Bf[cti][kc][1] = *(const short8*)&wb[fb + 512];
        }
      }
    }

    #pragma unroll
    for (int rt = 0; rt < 4; ++rt)
      #pragma unroll
      for (int cti = 0; cti < 2; ++cti)
        acc[rt][cti] = (f32x4){0.f, 0.f, 0.f, 0.f};

    // ---- MFMA main loop
    #pragma unroll
    for (int rt = 0; rt < 4; ++rt) {
      short8 Ahi[4], Alo[4];
      #pragma unroll
      for (int kc = 0; kc < 4; ++kc) {
        const int idx = ((rt * 4 + kc) * 64 + lane) * 8;
        Ahi[kc] = *(const short8*)&XT[idx];
        Alo[kc] = *(const short8*)&XT[8192 + idx];
      }
      #pragma unroll
      for (int kc = 0; kc < 4; ++kc) {
        #pragma unroll
        for (int cti = 0; cti < 2; ++cti) {
          f32x4 c = acc[rt][cti];
          c = __builtin_amdgcn_mfma_f32_16x16x32_bf16(Ahi[kc], Bf[cti][kc][0], c, 0, 0, 0);
          c = __builtin_amdgcn_mfma_f32_16x16x32_bf16(Ahi[kc], Bf[cti][kc][1], c, 0, 0, 0);
          c = __builtin_amdgcn_mfma_f32_16x16x32_bf16(Alo[kc], Bf[cti][kc][0], c, 0, 0, 0);
          c = __builtin_amdgcn_mfma_f32_16x16x32_bf16(Alo[kc], Bf[cti][kc][1], c, 0, 0, 0);
          acc[rt][cti] = c;
        }
      }
    }

    // ---- epilogue: + deg*wcol + bias, leaky_relu, exp (no max: |logit|<10)
    const float bias0 = bu[w * 32 + n],  bias1 = bu[w * 32 + 16 + n];
    const float wc0 = wcolp[conv * 128 + w * 32 + n];
    const float wc1 = wcolp[conv * 128 + w * 32 + 16 + n];

    #pragma unroll
    for (int rt = 0; rt < 4; ++rt) {
      const float4 dg = *(const float4*)&degs[rt * 16 + quad * 4];
      const float dgv[4] = {dg.x, dg.y, dg.z, dg.w};
      #pragma unroll
      for (int r = 0; r < 4; ++r) {
        float v0 = acc[rt][0][r] + bias0 + dgv[r] * wc0;
        float v1 = acc[rt][1][r] + bias1 + dgv[r] * wc1;
        v0 = (v0 > 0.f) ? v0 : 0.01f * v0;
        v1 = (v1 > 0.f) ? v1 : 0.01f * v1;
        const float e0 = __expf(v0), e1 = __expf(v1);
        acc[rt][0][r] = e0;
        acc[rt][1][r] = e1;
        float s = e0 + e1;
        s += __shfl_xor(s, 1);
        s += __shfl_xor(s, 2);
        s += __shfl_xor(s, 4);
        s += __shfl_xor(s, 8);
        if (n == 0) red[(rt * 16 + quad * 4 + r) * 4 + w] = s;
      }
    }
    __syncthreads();
    if (tid < 64) {
      const float4 p = *(const float4*)&red[tid * 4];
      invb[tid] = 1.f / (p.x + p.y + p.z + p.w);
    }
    __syncthreads();
    #pragma unroll
    for (int rt = 0; rt < 4; ++rt) {
      const float4 iv = *(const float4*)&invb[rt * 16 + quad * 4];
      const float ivv[4] = {iv.x, iv.y, iv.z, iv.w};
      #pragma unroll
      for (int r = 0; r < 4; ++r) {
        acc[rt][0][r] *= ivv[r];
        acc[rt][1][r] *= ivv[r];
      }
    }

    if (cv == 0) {
      // write y (hi/lo) back into XT in A-fragment order; y's col j is the
      // next conv's k:  kc=j>>5==w, quad'=(j&31)>>3, elem=j&7.
      #pragma unroll
      for (int rt = 0; rt < 4; ++rt) {
        #pragma unroll
        for (int cti = 0; cti < 2; ++cti) {
          const int lane2base = (cti * 2 + (n >> 3)) * 16;
          const int elem = n & 7;
          #pragma unroll
          for (int r = 0; r < 4; ++r) {
            const float v = acc[rt][cti][r];
            const unsigned short h = bf16h(v);
            const int idx = ((rt * 4 + w) * 64 + (lane2base + quad * 4 + r)) * 8 + elem;
            XT[idx] = h;
            XT[8192 + idx] = bf16h(v - bf16tof(h));
          }
        }
      }
      __syncthreads();
    }
  }

  // ---- scatter into per-graph sums (batch sorted: one-graph fast path)
  {
    bool fast = false; int gall = 0;
    if (mbase + 63 < NN) { gall = batch[mbase]; fast = (batch[mbase + 63] == gall); }
    if (fast) {
      #pragma unroll
      for (int cti = 0; cti < 2; ++cti) {
        float s = 0.f;
        #pragma unroll
        for (int rt = 0; rt < 4; ++rt)
          #pragma unroll
          for (int r = 0; r < 4; ++r) s += acc[rt][cti][r];
        s += __shfl_xor(s, 16);
        s += __shfl_xor(s, 32);
        if (quad == 0)
          atomicAdd(&gsum[gall * FD + w * 32 + cti * 16 + n], s);
      }
    } else {
      const int j0 = w * 32 + n, j1 = w * 32 + 16 + n;
      for (int rt = 0; rt < 4; ++rt) {
        for (int r = 0; r < 4; ++r) {
          const int node = mbase + rt * 16 + quad * 4 + r;
          if (node < NN) {
            const int g = batch[node];
            atomicAdd(&gsum[g * FD + j0], acc[rt][0][r]);
            atomicAdd(&gsum[g * FD + j1], acc[rt][1][r]);
          }
        }
      }
    }
  }
}

// -------------------------------------------------------------------------
// Final MLP: 8 blocks x 8 graphs.
// -------------------------------------------------------------------------
__global__ __launch_bounds__(256) void fc_kernel(
    const float* __restrict__ ez_sum, const float* __restrict__ iz_sum,
    const int* __restrict__ cnt,
    const float* __restrict__ fc1_w, const float* __restrict__ fc1_b,
    const float* __restrict__ fc2_w, const float* __restrict__ fc2_b,
    float* __restrict__ out)
{
  __shared__ float z8[8 * 256];
  __shared__ float h8[8 * 129];
  const int t = threadIdx.x;
  const int gbase = blockIdx.x * 8;

  for (int idx = t; idx < 8 * 256; idx += 256) {
    const int gl = idx >> 8, c = idx & 255;
    const int g = gbase + gl;
    const float denom = fmaxf((float)cnt[g], 1.0f);
    const float v = (c < 128 ? ez_sum[g * 128 + c] : iz_sum[g * 128 + (c - 128)]);
    z8[idx] = v / denom;
  }
  __syncthreads();

  {
    const int o = t & 127;
    const int gh = t >> 7;
    const float* w = fc1_w + (size_t)o * 256;
    float a0 = fc1_b[o], a1 = a0, a2 = a0, a3 = a0;
    const float* z0 = &z8[(gh * 4 + 0) * 256];
    const float* z1 = &z8[(gh * 4 + 1) * 256];
    const float* z2 = &z8[(gh * 4 + 2) * 256];
    const float* z3 = &z8[(gh * 4 + 3) * 256];
    for (int c = 0; c < 256; c += 4) {
      const float4 wv = *(const float4*)(w + c);
      const float4 v0 = *(const float4*)(z0 + c);
      const float4 v1 = *(const float4*)(z1 + c);
      const float4 v2 = *(const float4*)(z2 + c);
      const float4 v3 = *(const float4*)(z3 + c);
      a0 += wv.x * v0.x + wv.y * v0.y + wv.z * v0.z + wv.w * v0.w;
      a1 += wv.x * v1.x + wv.y * v1.y + wv.z * v1.z + wv.w * v1.w;
      a2 += wv.x * v2.x + wv.y * v2.y + wv.z * v2.z + wv.w * v2.w;
      a3 += wv.x * v3.x + wv.y * v3.y + wv.z * v3.z + wv.w * v3.w;
    }
    h8[(gh * 4 + 0) * 129 + o] = fmaxf(a0, 0.f);
    h8[(gh * 4 + 1) * 129 + o] = fmaxf(a1, 0.f);
    h8[(gh * 4 + 2) * 129 + o] = fmaxf(a2, 0.f);
    h8[(gh * 4 + 3) * 129 + o] = fmaxf(a3, 0.f);
  }
  __syncthreads();

  if (t < 8) {
    const float* hh = &h8[t * 129];
    float a = fc2_b[0];
    for (int o = 0; o < 128; ++o) a += hh[o] * fc2_w[o];
    out[gbase + t] = a;
  }
}

// -------------------------------------------------------------------------
extern "C" void kernel_launch(void* const* d_in, const int* in_sizes, int n_in,
                              void* d_out, int out_size, void* d_ws, size_t ws_size,
                              hipStream_t stream) {
  const float* x                   = (const float*)d_in[0];
  const int*   edge_index          = (const int*)  d_in[1];   // [2,E]: first E = sources
  const int*   internal_edge_index = (const int*)  d_in[3];
  const int*   batch               = (const int*)  d_in[5];
  const float* wu_e1 = (const float*)d_in[8];
  const float* bu_e1 = (const float*)d_in[9];
  const float* wu_e2 = (const float*)d_in[12];
  const float* bu_e2 = (const float*)d_in[13];
  const float* wu_i1 = (const float*)d_in[16];
  const float* bu_i1 = (const float*)d_in[17];
  const float* wu_i2 = (const float*)d_in[20];
  const float* bu_i2 = (const float*)d_in[21];
  const float* fc1_w = (const float*)d_in[22];
  const float* fc1_b = (const float*)d_in[23];
  const float* fc2_w = (const float*)d_in[24];
  const float* fc2_b = (const float*)d_in[25];

  char* ws = (char*)d_ws;
  int*   deg_ext = (int*)  (ws + DEG_EXT_OFF);
  int*   deg_int = (int*)  (ws + DEG_INT_OFF);
  float* ez      = (float*)(ws + EZ_OFF);
  float* iz      = (float*)(ws + IZ_OFF);
  int*   cnt     = (int*)  (ws + CNT_OFF);
  unsigned short* WB = (unsigned short*)(ws + WB_OFF);
  float* wcolp   = (float*)(ws + WCOL_OFF);

  hipMemsetAsync(d_ws, 0, ZERO_BYTES, stream);

  prep_hist_kernel<<<4 + HB_EXT + HB_INT + HB_BAT, 256, 0, stream>>>(
      wu_e1, wu_e2, wu_i1, wu_i2,
      edge_index, internal_edge_index, batch,
      WB, wcolp, deg_ext, deg_int, cnt);

  conv_mfma_kernel<<<dim3((NN + 63) / 64, 2), 256, 0, stream>>>(
      x, deg_ext, deg_int, batch, WB, wcolp,
      bu_e1, bu_e2, bu_i1, bu_i2, ez, iz);

  fc_kernel<<<8, 256, 0, stream>>>(ez, iz, cnt, fc1_w, fc1_b, fc2_w, fc2_b,
                                   (float*)d_out);
}